// Round 1
// baseline (15.508 us; speedup 1.0000x reference)
//
#include <hip/hip_runtime.h>
#include <math.h>

#define NB 8      // batch
#define ND 256    // sequence length (i, j)
#define NN 64     // channels ("heads", head_dim = 1)

// One block per (b, n) pair: computes q,k,v columns via 64-wide dots with 3
// columns of W, then a 256-way softmax-weighted average of v, all fused.
__global__ __launch_bounds__(256, 2)
void fused_mhsa_kernel(const float* __restrict__ x,
                       const float* __restrict__ W,
                       float* __restrict__ out) {
    const int bn = blockIdx.x;        // 0..511
    const int b  = bn >> 6;
    const int n  = bn & 63;
    const int i  = threadIdx.x;       // sequence row 0..255

    __shared__ float wq[NN], wk[NN], wv[NN];
    __shared__ __align__(16) float ks[ND];
    __shared__ __align__(16) float vs[ND];
    __shared__ float red[8];          // per-wave kmax (0..3), kmin (4..7)

    // ---- stage the three W columns (n, 64+n, 128+n) into LDS ----
    if (i < 3 * NN) {
        const int which = i >> 6;     // 0:q 1:k 2:v
        const int m     = i & 63;
        const float val = W[m * (3 * NN) + which * NN + n];
        if (which == 0)      wq[m] = val;
        else if (which == 1) wk[m] = val;
        else                 wv[m] = val;
    }
    __syncthreads();

    // ---- per-thread q_i, k_i, v_i: dot(x[b,i,:], w{q,k,v}) single pass ----
    const float4* xrow = reinterpret_cast<const float4*>(x + ((size_t)b * ND + i) * NN);
    float q = 0.f, k = 0.f, v = 0.f;
    #pragma unroll
    for (int m4 = 0; m4 < NN / 4; ++m4) {
        const float4 xv = xrow[m4];
        const int m = m4 * 4;
        q = fmaf(xv.x, wq[m+0], q); k = fmaf(xv.x, wk[m+0], k); v = fmaf(xv.x, wv[m+0], v);
        q = fmaf(xv.y, wq[m+1], q); k = fmaf(xv.y, wk[m+1], k); v = fmaf(xv.y, wv[m+1], v);
        q = fmaf(xv.z, wq[m+2], q); k = fmaf(xv.z, wk[m+2], k); v = fmaf(xv.z, wv[m+2], v);
        q = fmaf(xv.w, wq[m+3], q); k = fmaf(xv.w, wk[m+3], k); v = fmaf(xv.w, wv[m+3], v);
    }
    ks[i] = k;
    vs[i] = v;

    // ---- block reduce kmax/kmin (scores factorize: row max = qs*kmax or qs*kmin) ----
    float kmax = k, kmin = k;
    #pragma unroll
    for (int off = 32; off > 0; off >>= 1) {
        kmax = fmaxf(kmax, __shfl_xor(kmax, off));
        kmin = fminf(kmin, __shfl_xor(kmin, off));
    }
    const int wave = i >> 6;
    if ((i & 63) == 0) { red[wave] = kmax; red[4 + wave] = kmin; }
    __syncthreads();   // publishes ks/vs AND red
    kmax = fmaxf(fmaxf(red[0], red[1]), fmaxf(red[2], red[3]));
    kmin = fminf(fminf(red[4], red[5]), fminf(red[6], red[7]));

    // ---- softmax row i over j, fully from LDS broadcasts ----
    const float LOG2E = 1.4426950408889634f;
    const float scale = 0.125f;                  // 1/sqrt(64)
    const float qs = q * scale * LOG2E;          // exponent in log2 domain
    const float m2 = fmaxf(qs * kmax, qs * kmin);

    float sum = 0.f, acc = 0.f;
    const float4* k4 = reinterpret_cast<const float4*>(ks);
    const float4* v4 = reinterpret_cast<const float4*>(vs);
    #pragma unroll 4
    for (int j4 = 0; j4 < ND / 4; ++j4) {
        const float4 kv = k4[j4];
        const float4 vv = v4[j4];
        const float e0 = __builtin_amdgcn_exp2f(fmaf(qs, kv.x, -m2));
        const float e1 = __builtin_amdgcn_exp2f(fmaf(qs, kv.y, -m2));
        const float e2 = __builtin_amdgcn_exp2f(fmaf(qs, kv.z, -m2));
        const float e3 = __builtin_amdgcn_exp2f(fmaf(qs, kv.w, -m2));
        sum += (e0 + e1) + (e2 + e3);
        acc = fmaf(e0, vv.x, acc);
        acc = fmaf(e1, vv.y, acc);
        acc = fmaf(e2, vv.z, acc);
        acc = fmaf(e3, vv.w, acc);
    }

    out[((size_t)b * ND + i) * NN + n] = acc / sum;
}

extern "C" void kernel_launch(void* const* d_in, const int* in_sizes, int n_in,
                              void* d_out, int out_size, void* d_ws, size_t ws_size,
                              hipStream_t stream) {
    const float* x = (const float*)d_in[0];   // (8, 256, 64) fp32
    const float* W = (const float*)d_in[1];   // (64, 192) fp32
    float* out = (float*)d_out;               // (8, 256, 64) fp32

    dim3 grid(NB * NN);   // 512 blocks, one per (b, n)
    dim3 block(ND);       // 256 threads, one per sequence row
    fused_mhsa_kernel<<<grid, block, 0, stream>>>(x, W, out);
}